// Round 1
// 1056.576 us; speedup vs baseline: 1.0349x; 1.0349x over previous
//
#include <hip/hip_runtime.h>
#include <hip/hip_bf16.h>
#include <math.h>

typedef unsigned short ushort_t;
typedef __attribute__((ext_vector_type(8))) short bf16x8;   // 8 bf16 = 4 VGPRs
typedef __attribute__((ext_vector_type(4))) float f32x4;

#define SCALE_QK 0.04419417382415922f   // 1/sqrt(512)
#define PE_C 0.017988946039015986f      // ln(10000)/512

// ---------------------------------------------------------------------------
__device__ __forceinline__ void g2lds16(const void* g, void* l) {
    __builtin_amdgcn_global_load_lds(
        (const __attribute__((address_space(1))) unsigned int*)g,
        (__attribute__((address_space(3))) unsigned int*)l,
        16, 0, 0);
}
__device__ __forceinline__ ushort_t f2bs(float v) {
    __hip_bfloat16 h = __float2bfloat16(v);
    return *reinterpret_cast<ushort_t*>(&h);
}
__device__ __forceinline__ float bs2f(ushort_t v) {
    return __uint_as_float(((unsigned int)v) << 16);
}

// ---------------------------------------------------------------------------
// bf16 MFMA GEMM, BK=64 with XOR-swizzled staging (swizzle folded into the
// GLOBAL k-offset since global_load_lds can't scatter; LDS[row][c] holds
// global chunk c^(row&7), so frag reads are 2-way-bank = free).
// A: [m][k] (lda), B: [n][k] (ldb, pre-transposed), C bf16 [m][n] (ldc).
// VT: blocks with n0>=1024 (QKV's V region) write transposed into vt[bh][vd][s].
// STATS: also emit per-(row,wave) float2(sum,sumsq) to part[m*16 + bx*2 + (w&1)].
template<int BM, int BN, bool RELU, bool VT, bool STATS>
__global__ __launch_bounds__(256) void gemm2(
    const ushort_t* __restrict__ A, const ushort_t* __restrict__ B,
    const float* __restrict__ bias, const ushort_t* __restrict__ resb,
    ushort_t* __restrict__ C, float2* __restrict__ part,
    ushort_t* __restrict__ vt, int K, int lda, int ldb, int ldc)
{
    constexpr int MI = BM / 32, NJ = BN / 32;
    __shared__ ushort_t As[BM * 64];
    __shared__ ushort_t Bs[BN * 64];

    const int t = threadIdx.x;
    const int lane = t & 63, w = t >> 6;
    const int l16 = lane & 15, quad = lane >> 4;
    const int r8 = lane >> 3;                 // 0..7 row within 8-row inst
    const int kg = ((lane & 7) ^ r8) << 3;    // swizzled global k-chunk offset
    const int wm = (w >> 1) * (BM / 2);
    const int wn = (w & 1) * (BN / 2);

    const int m0 = blockIdx.y * BM, n0 = blockIdx.x * BN;

    f32x4 acc[MI][NJ];
    #pragma unroll
    for (int i = 0; i < MI; i++)
        #pragma unroll
        for (int j = 0; j < NJ; j++)
            acc[i][j] = (f32x4){0.f, 0.f, 0.f, 0.f};

    for (int k0 = 0; k0 < K; k0 += 64) {
        #pragma unroll
        for (int ii = 0; ii < BM / 32; ii++) {          // BM/8 insts over 4 waves
            int rbase = w * (BM / 4) + ii * 8;
            g2lds16(A + (size_t)(m0 + rbase + r8) * lda + k0 + kg, &As[rbase * 64]);
        }
        #pragma unroll
        for (int ii = 0; ii < BN / 32; ii++) {
            int rbase = w * (BN / 4) + ii * 8;
            g2lds16(B + (size_t)(n0 + rbase + r8) * ldb + k0 + kg, &Bs[rbase * 64]);
        }
        __syncthreads();

        #pragma unroll
        for (int tt = 0; tt < 2; tt++) {
            bf16x8 af[MI], bf[NJ];
            #pragma unroll
            for (int i = 0; i < MI; i++) {
                int row = wm + i * 16 + l16;
                af[i] = *(const bf16x8*)&As[row * 64 + ((((tt << 2) + quad) ^ (row & 7)) << 3)];
            }
            #pragma unroll
            for (int j = 0; j < NJ; j++) {
                int row = wn + j * 16 + l16;
                bf[j] = *(const bf16x8*)&Bs[row * 64 + ((((tt << 2) + quad) ^ (row & 7)) << 3)];
            }
            #pragma unroll
            for (int i = 0; i < MI; i++)
                #pragma unroll
                for (int j = 0; j < NJ; j++)
                    acc[i][j] = __builtin_amdgcn_mfma_f32_16x16x32_bf16(
                        af[i], bf[j], acc[i][j], 0, 0, 0);
        }
        __syncthreads();
    }

    // ---- epilogue ----
    if (VT && n0 >= 1024) {
        // V region: write transposed into vt[bh][vd][s], 4 consecutive s per lane
        #pragma unroll
        for (int i = 0; i < MI; i++) {
            int mbase = m0 + wm + i * 16 + quad * 4;
            int b = mbase >> 9, s = mbase & 511;
            #pragma unroll
            for (int j = 0; j < NJ; j++) {
                int n = n0 + wn + j * 16 + l16;
                int hv = n - 1024;
                int h = hv >> 6, vd = hv & 63;
                float bv = bias[n];
                ushort4 pk;
                pk.x = f2bs(acc[i][j][0] + bv);
                pk.y = f2bs(acc[i][j][1] + bv);
                pk.z = f2bs(acc[i][j][2] + bv);
                pk.w = f2bs(acc[i][j][3] + bv);
                *(ushort4*)&vt[((size_t)((b << 3) + h)) * 32768 + (size_t)vd * 512 + s] = pk;
            }
        }
        return;
    }

    #pragma unroll
    for (int i = 0; i < MI; i++) {
        float rs[4] = {0.f, 0.f, 0.f, 0.f}, rq[4] = {0.f, 0.f, 0.f, 0.f};
        #pragma unroll
        for (int j = 0; j < NJ; j++) {
            int n = n0 + wn + j * 16 + l16;
            float bv = bias ? bias[n] : 0.f;
            #pragma unroll
            for (int r = 0; r < 4; r++) {
                int m = m0 + wm + i * 16 + quad * 4 + r;
                float v = acc[i][j][r] + bv;
                if (resb) v += bs2f(resb[(size_t)m * ldc + n]);
                if (RELU) v = fmaxf(v, 0.f);
                C[(size_t)m * ldc + n] = f2bs(v);
                if (STATS) { rs[r] += v; rq[r] += v * v; }
            }
        }
        if (STATS) {
            #pragma unroll
            for (int r = 0; r < 4; r++) {
                float s = rs[r], q = rq[r];
                #pragma unroll
                for (int off = 1; off < 16; off <<= 1) {
                    s += __shfl_xor(s, off);
                    q += __shfl_xor(q, off);
                }
                if (l16 == 0) {
                    int m = m0 + wm + i * 16 + quad * 4 + r;
                    part[(size_t)m * 16 + blockIdx.x * 2 + (w & 1)] = make_float2(s, q);
                }
            }
        }
    }
}

// ---------------------------------------------------------------------------
// 256x256 / 8-wave GEMM with counted-vmcnt cross-barrier pipeline (T3/T4 min
// form). Wave-tile 128x64 (MI=8,NJ=4) -> fragment LDS traffic 0.49 KB/MFLOP
// (vs 0.97 at 128^2), MFMA-bound balance. LDS double-buffer 128 KiB; loads
// for tile kt+2 issued after a RAW barrier and waited with vmcnt(8) -- 8
// loads stay in flight across every barrier (never drain to 0 mid-loop).
// Safety: every ds_read is consumed by an MFMA before the trailing barrier
// (compiler's auto-lgkmcnt), so raw s_barrier needs no lgkm drain; asm
// memory fences pin g2lds/ds_read on the correct side of each barrier.
// Requires K >= 128 (NT >= 2); staging/swizzle identical to gemm2.
template<bool RELU, bool VT>
__global__ __launch_bounds__(512, 2) void gemm8(
    const ushort_t* __restrict__ A, const ushort_t* __restrict__ B,
    const float* __restrict__ bias, ushort_t* __restrict__ C,
    ushort_t* __restrict__ vt, int K, int lda, int ldb, int ldc)
{
    __shared__ ushort_t As[2][256 * 64];
    __shared__ ushort_t Bs[2][256 * 64];

    const int t = threadIdx.x;
    const int lane = t & 63, w = t >> 6;        // 8 waves
    const int l16 = lane & 15, quad = lane >> 4;
    const int r8 = lane >> 3;
    const int kg = ((lane & 7) ^ r8) << 3;      // swizzled global k-chunk
    const int wm = (w >> 2) * 128;              // 2 wave-rows (M)
    const int wn = (w & 3) * 64;                // 4 wave-cols (N)
    const int m0 = blockIdx.y * 256, n0 = blockIdx.x * 256;
    const int NT = K >> 6;

    f32x4 acc[8][4];
    #pragma unroll
    for (int i = 0; i < 8; i++)
        #pragma unroll
        for (int j = 0; j < 4; j++)
            acc[i][j] = (f32x4){0.f, 0.f, 0.f, 0.f};

    auto STAGE8 = [&](int kt, int bb) {
        int k0 = kt << 6;
        #pragma unroll
        for (int ii = 0; ii < 4; ii++) {        // 8 waves x 32 rows = 256
            int rbase = w * 32 + ii * 8;
            g2lds16(A + (size_t)(m0 + rbase + r8) * lda + k0 + kg,
                    &As[bb][rbase * 64]);
            g2lds16(B + (size_t)(n0 + rbase + r8) * ldb + k0 + kg,
                    &Bs[bb][rbase * 64]);
        }
    };

    STAGE8(0, 0);
    STAGE8(1, 1);

    for (int kt = 0; kt < NT; kt++) {
        const int bb = kt & 1;
        // steady state: {kt:8, kt+1:8} outstanding -> wait until only 8 left
        if (kt < NT - 1)
            asm volatile("s_waitcnt vmcnt(8)" ::: "memory");
        else
            asm volatile("s_waitcnt vmcnt(0)" ::: "memory");
        __builtin_amdgcn_s_barrier();           // all waves confirmed tile kt
        asm volatile("" ::: "memory");

        #pragma unroll
        for (int tt = 0; tt < 2; tt++) {
            bf16x8 af[8], bf[4];
            #pragma unroll
            for (int i = 0; i < 8; i++) {
                int row = wm + i * 16 + l16;
                af[i] = *(const bf16x8*)&As[bb][row * 64 + ((((tt << 2) + quad) ^ (row & 7)) << 3)];
            }
            #pragma unroll
            for (int j = 0; j < 4; j++) {
                int row = wn + j * 16 + l16;
                bf[j] = *(const bf16x8*)&Bs[bb][row * 64 + ((((tt << 2) + quad) ^ (row & 7)) << 3)];
            }
            #pragma unroll
            for (int i = 0; i < 8; i++)
                #pragma unroll
                for (int j = 0; j < 4; j++)
                    acc[i][j] = __builtin_amdgcn_mfma_f32_16x16x32_bf16(
                        af[i], bf[j], acc[i][j], 0, 0, 0);
        }

        // raw barrier: all waves done reading buf bb (reads drained by MFMA
        // lgkm deps); then overwrite it with tile kt+2 -- loads fly under the
        // next tile's compute.
        asm volatile("" ::: "memory");
        __builtin_amdgcn_s_barrier();
        asm volatile("" ::: "memory");
        if (kt + 2 < NT)
            STAGE8(kt + 2, bb);
    }

    // ---- epilogue ----
    if (VT && n0 >= 1024) {
        #pragma unroll
        for (int i = 0; i < 8; i++) {
            int mbase = m0 + wm + i * 16 + quad * 4;
            int b = mbase >> 9, s = mbase & 511;
            #pragma unroll
            for (int j = 0; j < 4; j++) {
                int n = n0 + wn + j * 16 + l16;
                int hv = n - 1024;
                int h = hv >> 6, vd = hv & 63;
                float bv = bias[n];
                ushort4 pk;
                pk.x = f2bs(acc[i][j][0] + bv);
                pk.y = f2bs(acc[i][j][1] + bv);
                pk.z = f2bs(acc[i][j][2] + bv);
                pk.w = f2bs(acc[i][j][3] + bv);
                *(ushort4*)&vt[((size_t)((b << 3) + h)) * 32768 + (size_t)vd * 512 + s] = pk;
            }
        }
        return;
    }

    #pragma unroll
    for (int i = 0; i < 8; i++)
        #pragma unroll
        for (int j = 0; j < 4; j++) {
            int n = n0 + wn + j * 16 + l16;
            float bv = bias[n];
            #pragma unroll
            for (int r = 0; r < 4; r++) {
                int m = m0 + wm + i * 16 + quad * 4 + r;
                float v = acc[i][j][r] + bv;
                if (RELU) v = fmaxf(v, 0.f);
                C[(size_t)m * ldc + n] = f2bs(v);
            }
        }
}

// ---------------------------------------------------------------------------
// Fused flash attention (unchanged): one (b,h), 128 q rows/block,
// 4 key-chunks of 128, fixed softmax reference m=0, ctx in-place into Q slice.
__global__ __launch_bounds__(256) void flash_attn(
    ushort_t* __restrict__ QKV, const ushort_t* __restrict__ Vt,
    const int* __restrict__ tok)
{
    __shared__ ushort_t Qs[128 * 64];
    __shared__ ushort_t Ks[128 * 64];
    __shared__ ushort_t Vts[64 * 128];
    __shared__ ushort_t Ps[128 * 128];

    const int bh = blockIdx.y;
    const int b = bh >> 3, h = bh & 7;
    const int q0 = blockIdx.x * 128;
    const int t = threadIdx.x;
    const int lane = t & 63, w = t >> 6;
    const int l16 = lane & 15, quad = lane >> 4;
    const int wm = w * 32;
    const size_t rowbase = (size_t)b * 512;

    {
        int r8 = lane >> 3;
        int kg = (lane & 7) ^ r8;
        #pragma unroll
        for (int ii = 0; ii < 4; ii++) {
            int rb = w * 32 + ii * 8;
            g2lds16(QKV + (rowbase + q0 + rb + r8) * 1536 + h * 64 + kg * 8,
                    &Qs[rb * 64]);
        }
    }

    f32x4 accO[2][4];
    #pragma unroll
    for (int i = 0; i < 2; i++)
        #pragma unroll
        for (int jv = 0; jv < 4; jv++)
            accO[i][jv] = (f32x4){0.f, 0.f, 0.f, 0.f};
    float lrow[2][4];
    #pragma unroll
    for (int i = 0; i < 2; i++)
        #pragma unroll
        for (int r = 0; r < 4; r++) lrow[i][r] = 0.f;

    for (int kc = 0; kc < 4; kc++) {
        __syncthreads();
        {
            int r8 = lane >> 3;
            int kg = (lane & 7) ^ r8;
            #pragma unroll
            for (int ii = 0; ii < 4; ii++) {
                int rb = w * 32 + ii * 8;
                g2lds16(QKV + (rowbase + kc * 128 + rb + r8) * 1536 + 512 + h * 64 + kg * 8,
                        &Ks[rb * 64]);
            }
        }
        {
            int v4 = lane >> 4;
            #pragma unroll
            for (int ii = 0; ii < 4; ii++) {
                int vb = w * 16 + ii * 4;
                int vd = vb + v4;
                int kg = (lane & 15) ^ (vd & 15);
                g2lds16(Vt + (size_t)bh * 32768 + (size_t)vd * 512 + kc * 128 + kg * 8,
                        &Vts[vb * 128]);
            }
        }
        float maskv[8];
        #pragma unroll
        for (int j = 0; j < 8; j++)
            maskv[j] = (tok[b * 512 + kc * 128 + j * 16 + l16] == 0) ? -1e9f : 0.f;

        __syncthreads();

        f32x4 sacc[2][8];
        #pragma unroll
        for (int i = 0; i < 2; i++)
            #pragma unroll
            for (int j = 0; j < 8; j++)
                sacc[i][j] = (f32x4){0.f, 0.f, 0.f, 0.f};
        #pragma unroll
        for (int tt = 0; tt < 2; tt++) {
            bf16x8 aq[2], bk8[8];
            #pragma unroll
            for (int i = 0; i < 2; i++) {
                int row = wm + i * 16 + l16;
                aq[i] = *(const bf16x8*)&Qs[row * 64 + (((tt << 2) + quad) ^ (row & 7)) * 8];
            }
            #pragma unroll
            for (int j = 0; j < 8; j++) {
                int row = j * 16 + l16;
                bk8[j] = *(const bf16x8*)&Ks[row * 64 + (((tt << 2) + quad) ^ (row & 7)) * 8];
            }
            #pragma unroll
            for (int i = 0; i < 2; i++)
                #pragma unroll
                for (int j = 0; j < 8; j++)
                    sacc[i][j] = __builtin_amdgcn_mfma_f32_16x16x32_bf16(
                        aq[i], bk8[j], sacc[i][j], 0, 0, 0);
        }

        #pragma unroll
        for (int i = 0; i < 2; i++)
            #pragma unroll
            for (int j = 0; j < 8; j++)
                #pragma unroll
                for (int r = 0; r < 4; r++) {
                    float p = __expf(fmaf(sacc[i][j][r], SCALE_QK, maskv[j]));
                    sacc[i][j][r] = p;
                    lrow[i][r] += p;
                }

        #pragma unroll
        for (int i = 0; i < 2; i++)
            #pragma unroll
            for (int j = 0; j < 8; j++) {
                int col = j * 16 + l16;
                int colc = col >> 3, csub = col & 7;
                #pragma unroll
                for (int r = 0; r < 4; r++) {
                    int row = wm + i * 16 + quad * 4 + r;
                    Ps[row * 128 + ((colc ^ (row & 15)) << 3) + csub] = f2bs(sacc[i][j][r]);
                }
            }

        #pragma unroll
        for (int tt = 0; tt < 4; tt++) {
            bf16x8 ap[2], bv8[4];
            #pragma unroll
            for (int i = 0; i < 2; i++) {
                int row = wm + i * 16 + l16;
                ap[i] = *(const bf16x8*)&Ps[row * 128 + ((((tt << 2) + quad)) ^ (row & 15)) * 8];
            }
            #pragma unroll
            for (int jv = 0; jv < 4; jv++) {
                int vd = jv * 16 + l16;
                bv8[jv] = *(const bf16x8*)&Vts[vd * 128 + (((tt << 2) + quad) ^ (vd & 15)) * 8];
            }
            #pragma unroll
            for (int i = 0; i < 2; i++)
                #pragma unroll
                for (int jv = 0; jv < 4; jv++)
                    accO[i][jv] = __builtin_amdgcn_mfma_f32_16x16x32_bf16(
                        ap[i], bv8[jv], accO[i][jv], 0, 0, 0);
        }
    }

    #pragma unroll
    for (int i = 0; i < 2; i++)
        #pragma unroll
        for (int r = 0; r < 4; r++) {
            float s = lrow[i][r];
            #pragma unroll
            for (int off = 1; off < 16; off <<= 1)
                s += __shfl_xor(s, off);
            float inv = 1.f / s;
            int row = q0 + wm + i * 16 + quad * 4 + r;
            #pragma unroll
            for (int jv = 0; jv < 4; jv++) {
                int vd = jv * 16 + l16;
                QKV[(rowbase + row) * 1536 + h * 64 + vd] = f2bs(accO[i][jv][r] * inv);
            }
        }
}

// ---------------------------------------------------------------------------
__global__ __launch_bounds__(256) void transpose_cvt(
    const float* __restrict__ in, __hip_bfloat16* __restrict__ out,
    int R, int Cc, long long inz, long long outz)
{
    in  += blockIdx.z * inz;
    out += blockIdx.z * outz;
    __shared__ float tile[32][33];
    int c0 = blockIdx.x * 32, r0 = blockIdx.y * 32;
    int tx = threadIdx.x & 31, ty = threadIdx.x >> 5;
    #pragma unroll
    for (int i = 0; i < 4; i++)
        tile[ty + i * 8][tx] = in[(size_t)(r0 + ty + i * 8) * Cc + c0 + tx];
    __syncthreads();
    #pragma unroll
    for (int i = 0; i < 4; i++)
        out[(size_t)(c0 + ty + i * 8) * R + r0 + tx] =
            __float2bfloat16(tile[tx][ty + i * 8]);
}

__global__ __launch_bounds__(256) void concat_bias(const float* __restrict__ bq,
                                                   const float* __restrict__ bk,
                                                   const float* __restrict__ bv,
                                                   float* __restrict__ bqkv) {
    int idx = blockIdx.x * 256 + threadIdx.x;
    if (idx >= 4 * 1536) return;
    int l = idx / 1536, n = idx - l * 1536;
    float v = (n < 512) ? bq[l * 512 + n]
            : (n < 1024) ? bk[l * 512 + n - 512]
                         : bv[l * 512 + n - 1024];
    bqkv[idx] = v;
}

__global__ __launch_bounds__(256) void embed_pe_b(const int* __restrict__ tok,
                                                  const float* __restrict__ emb,
                                                  __hip_bfloat16* __restrict__ xb) {
    int idx = blockIdx.x * 256 + threadIdx.x;
    int d  = idx & 511;
    int bs = idx >> 9;
    int s  = bs & 511;
    int t  = tok[bs];
    float freq  = expf(-(float)(d & ~1) * PE_C);
    float angle = (float)s * freq;
    float pe    = (d & 1) ? cosf(angle) : sinf(angle);
    xb[idx] = __float2bfloat16(emb[(size_t)t * 512 + d] + pe);
}

// ---------------------------------------------------------------------------
// LN from fused stats: part[row][16] float2 partial (sum,sumsq); Cpre bf16.
__global__ __launch_bounds__(256) void ln_stats(const ushort_t* __restrict__ Cpre,
                                                const float2* __restrict__ part,
                                                const float* __restrict__ g,
                                                const float* __restrict__ b,
                                                ushort_t* __restrict__ Xb) {
    long long row = blockIdx.x;
    int t = threadIdx.x;
    float s = 0.f, q = 0.f;
    if (t < 16) {
        float2 p = part[row * 16 + t];
        s = p.x; q = p.y;
    }
    #pragma unroll
    for (int off = 1; off < 16; off <<= 1) {
        s += __shfl_xor(s, off);
        q += __shfl_xor(q, off);
    }
    __shared__ float mv[2];
    if (t == 0) {
        float mean = s * (1.f / 512.f);
        float var = q * (1.f / 512.f) - mean * mean;
        mv[0] = mean;
        mv[1] = rsqrtf(var + 1e-5f);
    }
    __syncthreads();
    float mean = mv[0], r = mv[1];
    int c = t * 2;
    ushort2 u = *(const ushort2*)&Cpre[row * 512 + c];
    ushort2 o;
    o.x = f2bs((bs2f(u.x) - mean) * r * g[c]     + b[c]);
    o.y = f2bs((bs2f(u.y) - mean) * r * g[c + 1] + b[c + 1]);
    *(ushort2*)&Xb[row * 512 + c] = o;
}

// ---------------------------------------------------------------------------
// head stage 1: 512 k-slices of 512; partials to FbP[slice*8+kh][2048]
__global__ __launch_bounds__(256) void feat_partial(const ushort_t* __restrict__ Xb,
                                                    const float* __restrict__ Wf,
                                                    float* __restrict__ FbP) {
    int slice = blockIdx.x;
    int k0 = slice * 512;
    __shared__ float Xs[16][512];
    int t = threadIdx.x;
    for (int i = t; i < 2048; i += 256) {
        int b = i >> 7, c4 = (i & 127) * 4;
        ushort4 u = *(const ushort4*)&Xb[(size_t)b * 262144 + k0 + c4];
        Xs[b][c4 + 0] = bs2f(u.x);
        Xs[b][c4 + 1] = bs2f(u.y);
        Xs[b][c4 + 2] = bs2f(u.z);
        Xs[b][c4 + 3] = bs2f(u.w);
    }
    __syncthreads();
    int n4 = (t & 31) * 4;
    int kh = t >> 5;
    float4 acc[16];
    #pragma unroll
    for (int b = 0; b < 16; b++) acc[b] = (float4){0.f, 0.f, 0.f, 0.f};
    for (int kk4 = 0; kk4 < 16; kk4++) {
        int kb = kh * 64 + kk4 * 4;
        float4 w0 = *(const float4*)&Wf[(size_t)(k0 + kb + 0) * 128 + n4];
        float4 w1 = *(const float4*)&Wf[(size_t)(k0 + kb + 1) * 128 + n4];
        float4 w2 = *(const float4*)&Wf[(size_t)(k0 + kb + 2) * 128 + n4];
        float4 w3 = *(const float4*)&Wf[(size_t)(k0 + kb + 3) * 128 + n4];
        #pragma unroll
        for (int b = 0; b < 16; b++) {
            float4 xq = *(const float4*)&Xs[b][kb];
            acc[b].x += xq.x * w0.x + xq.y * w1.x + xq.z * w2.x + xq.w * w3.x;
            acc[b].y += xq.x * w0.y + xq.y * w1.y + xq.z * w2.y + xq.w * w3.y;
            acc[b].z += xq.x * w0.z + xq.y * w1.z + xq.z * w2.z + xq.w * w3.z;
            acc[b].w += xq.x * w0.w + xq.y * w1.w + xq.z * w2.w + xq.w * w3.w;
        }
    }
    float* dst = FbP + ((size_t)slice * 8 + kh) * 2048;
    #pragma unroll
    for (int b = 0; b < 16; b++)
        *(float4*)&dst[b * 128 + n4] = acc[b];
}

__global__ __launch_bounds__(256) void feat_reduce(const float* __restrict__ FbP,
                                                   float* __restrict__ Fb) {
    int idx = blockIdx.x * 256 + threadIdx.x;
    int j0 = blockIdx.y * 128;
    float s = 0.f;
    for (int j = 0; j < 128; j++) s += FbP[(size_t)(j0 + j) * 2048 + idx];
    atomicAdd(&Fb[idx], s);
}

// out: [0..15]=y_score, [16..31]=y_pred, [32..2079]=features
__global__ __launch_bounds__(256) void head_kernel(const float* __restrict__ feat,
                                                   const float* __restrict__ bfv,
                                                   const float* __restrict__ Wo2,
                                                   const float* __restrict__ bo2,
                                                   float* __restrict__ out) {
    __shared__ float f[2048];
    int t = threadIdx.x;
    for (int i = t; i < 2048; i += 256) {
        float v = feat[i] + bfv[i & 127];
        f[i] = v;
        out[32 + i] = v;
    }
    __syncthreads();
    if (t < 16) {
        float zv = bo2[0];
        for (int n = 0; n < 128; n++) zv = fmaf(f[t * 128 + n], Wo2[n], zv);
        float ys = 1.f / (1.f + expf(-zv));
        out[t] = ys;
        out[16 + t] = rintf(ys);
    }
}

// ---------------------------------------------------------------------------
extern "C" void kernel_launch(void* const* d_in, const int* in_sizes, int n_in,
                              void* d_out, int out_size, void* d_ws, size_t ws_size,
                              hipStream_t stream) {
    const int*   enc  = (const int*)  d_in[0];
    const float* emb  = (const float*)d_in[1];
    const float* Wq   = (const float*)d_in[2];
    const float* bq   = (const float*)d_in[3];
    const float* Wk   = (const float*)d_in[4];
    const float* bk   = (const float*)d_in[5];
    const float* Wv   = (const float*)d_in[6];
    const float* bv   = (const float*)d_in[7];
    const float* Wo   = (const float*)d_in[8];
    const float* bo   = (const float*)d_in[9];
    const float* g1   = (const float*)d_in[10];
    const float* be1  = (const float*)d_in[11];
    const float* W1   = (const float*)d_in[12];
    const float* b1f  = (const float*)d_in[13];
    const float* W2   = (const float*)d_in[14];
    const float* b2f  = (const float*)d_in[15];
    const float* g2   = (const float*)d_in[16];
    const float* be2  = (const float*)d_in[17];
    const float* Wf   = (const float*)d_in[18];
    const float* bf   = (const float*)d_in[19];
    const float* Wout = (const float*)d_in[20];
    const float* bout = (const float*)d_in[21];
    float* out = (float*)d_out;

    // ---- workspace layout (bytes), peak < 119 MB ----
    char* ws = (char*)d_ws;
    ushort_t* Cpre = (ushort_t*) (ws + 0);           // [8192,512] bf16 pre-LN
    ushort_t* Xb   = (ushort_t*) (ws + 16777216);    // [8192,512] bf16 activations
    ushort_t* QKV  = (ushort_t*) (ws + 25165824);    // [8192,1536] bf16
    ushort_t* Vt   = (ushort_t*) (ws + 50331648);    // [128][64][512] bf16
    ushort_t* S    = (ushort_t*) (ws + 58720256);    // FFN hidden [8192][2048] bf16
    ushort_t* WqkvT= (ushort_t*) (ws + 92274688);    // [4][1536][512] bf16
    ushort_t* WoT  = (ushort_t*) (ws + 98566144);    // [4][512][512] bf16
    ushort_t* W1T  = (ushort_t*) (ws + 100663296);   // [4][2048][512] bf16
    ushort_t* W2T  = (ushort_t*) (ws + 109051904);   // [4][512][2048] bf16
    float*    bqkv = (float*)    (ws + 117440512);   // [4][1536]
    float*    Fb   = (float*)    (ws + 117465088);   // [16][128]
    float2*   part = (float2*)   (ws + 117473280);   // [8192][16] LN stat partials
    float*    FbP  = (float*)    (ws + 25165824);    // head partials (aliases QKV/Vt)

    typedef __hip_bfloat16 bf16;

    transpose_cvt<<<dim3(16, 16, 4), 256, 0, stream>>>(Wq, (bf16*)WqkvT,            512, 512,  262144, 786432);
    transpose_cvt<<<dim3(16, 16, 4), 256, 0, stream>>>(Wk, (bf16*)(WqkvT + 262144), 512, 512,  262144, 786432);
    transpose_cvt<<<dim3(16, 16, 4), 256, 0, stream>>>(Wv, (bf16*)(WqkvT + 524288), 512, 512,  262144, 786432);
    transpose_cvt<<<dim3(16, 16, 4), 256, 0, stream>>>(Wo, (bf16*)WoT,              512, 512,  262144, 262144);
    transpose_cvt<<<dim3(64, 16, 4), 256, 0, stream>>>(W1, (bf16*)W1T,              512, 2048, 1048576, 1048576);
    transpose_cvt<<<dim3(16, 64, 4), 256, 0, stream>>>(W2, (bf16*)W2T,              2048, 512, 1048576, 1048576);
    concat_bias<<<24, 256, 0, stream>>>(bq, bk, bv, bqkv);

    embed_pe_b<<<16384, 256, 0, stream>>>(enc, emb, (bf16*)Xb);

    for (int l = 0; l < 4; l++) {
        // QKV: [8192,512]x[512,1536] on the 256^2 pipelined GEMM;
        // V columns go transposed straight to Vt
        gemm8<false, true><<<dim3(6, 32), 512, 0, stream>>>(
            Xb, WqkvT + (size_t)l * 786432, bqkv + l * 1536,
            QKV, Vt, 512, 512, 512, 1536);

        flash_attn<<<dim3(4, 128), 256, 0, stream>>>(QKV, Vt, enc);

        // Wo: ctx @ WoT + bo + Xb -> Cpre bf16 + LN stats (N=512: stays on gemm2)
        gemm2<128, 64, false, false, true><<<dim3(8, 64), 256, 0, stream>>>(
            QKV, WoT + (size_t)l * 262144, bo + l * 512, Xb,
            Cpre, part, nullptr, 512, 1536, 512, 512);
        ln_stats<<<8192, 256, 0, stream>>>(Cpre, part, g1 + l * 512, be1 + l * 512, Xb);

        // FFN1: relu(Xb @ W1T + b1) -> S bf16 (256 blocks = 1/CU, pipelined)
        gemm8<true, false><<<dim3(8, 32), 512, 0, stream>>>(
            Xb, W1T + (size_t)l * 1048576, b1f + l * 2048,
            S, nullptr, 512, 512, 512, 2048);
        // FFN2: S @ W2T + b2 + Xb -> Cpre bf16 + LN stats (N=512: stays on gemm2)
        gemm2<128, 64, false, false, true><<<dim3(8, 64), 256, 0, stream>>>(
            S, W2T + (size_t)l * 1048576, b2f + l * 512, Xb,
            Cpre, part, nullptr, 2048, 2048, 2048, 512);
        ln_stats<<<8192, 256, 0, stream>>>(Cpre, part, g2 + l * 512, be2 + l * 512, Xb);
    }

    hipMemsetAsync(Fb, 0, 2048 * sizeof(float), stream);
    feat_partial<<<512, 256, 0, stream>>>(Xb, Wf, FbP);
    feat_reduce<<<dim3(8, 32), 256, 0, stream>>>(FbP, Fb);
    head_kernel<<<1, 256, 0, stream>>>(Fb, bf, Wout, bout, out);
}

// Round 2
// 987.880 us; speedup vs baseline: 1.1068x; 1.0695x over previous
//
#include <hip/hip_runtime.h>
#include <hip/hip_bf16.h>
#include <math.h>

typedef unsigned short ushort_t;
typedef __attribute__((ext_vector_type(8))) short bf16x8;   // 8 bf16 = 4 VGPRs
typedef __attribute__((ext_vector_type(4))) float f32x4;

#define SCALE_QK 0.04419417382415922f   // 1/sqrt(512)
#define PE_C 0.017988946039015986f      // ln(10000)/512

// ---------------------------------------------------------------------------
__device__ __forceinline__ void g2lds16(const void* g, void* l) {
    __builtin_amdgcn_global_load_lds(
        (const __attribute__((address_space(1))) unsigned int*)g,
        (__attribute__((address_space(3))) unsigned int*)l,
        16, 0, 0);
}
__device__ __forceinline__ ushort_t f2bs(float v) {
    __hip_bfloat16 h = __float2bfloat16(v);
    return *reinterpret_cast<ushort_t*>(&h);
}
__device__ __forceinline__ float bs2f(ushort_t v) {
    return __uint_as_float(((unsigned int)v) << 16);
}

// ---------------------------------------------------------------------------
// 256x256 / 8-wave GEMM with counted-vmcnt cross-barrier pipeline.
// Wave-tile 128x64 (MI=8,NJ=4). LDS double-buffer 128 KiB; loads for tile
// kt+2 issued after a RAW barrier and waited with vmcnt(8) -- 8 loads stay
// in flight across every barrier (never drain to 0 mid-loop).
template<bool RELU, bool VT>
__global__ __launch_bounds__(512, 2) void gemm8(
    const ushort_t* __restrict__ A, const ushort_t* __restrict__ B,
    const float* __restrict__ bias, ushort_t* __restrict__ C,
    ushort_t* __restrict__ vt, int K, int lda, int ldb, int ldc)
{
    __shared__ ushort_t As[2][256 * 64];
    __shared__ ushort_t Bs[2][256 * 64];

    const int t = threadIdx.x;
    const int lane = t & 63, w = t >> 6;        // 8 waves
    const int l16 = lane & 15, quad = lane >> 4;
    const int r8 = lane >> 3;
    const int kg = ((lane & 7) ^ r8) << 3;      // swizzled global k-chunk
    const int wm = (w >> 2) * 128;              // 2 wave-rows (M)
    const int wn = (w & 3) * 64;                // 4 wave-cols (N)
    const int m0 = blockIdx.y * 256, n0 = blockIdx.x * 256;
    const int NT = K >> 6;

    f32x4 acc[8][4];
    #pragma unroll
    for (int i = 0; i < 8; i++)
        #pragma unroll
        for (int j = 0; j < 4; j++)
            acc[i][j] = (f32x4){0.f, 0.f, 0.f, 0.f};

    auto STAGE8 = [&](int kt, int bb) {
        int k0 = kt << 6;
        #pragma unroll
        for (int ii = 0; ii < 4; ii++) {        // 8 waves x 32 rows = 256
            int rbase = w * 32 + ii * 8;
            g2lds16(A + (size_t)(m0 + rbase + r8) * lda + k0 + kg,
                    &As[bb][rbase * 64]);
            g2lds16(B + (size_t)(n0 + rbase + r8) * ldb + k0 + kg,
                    &Bs[bb][rbase * 64]);
        }
    };

    STAGE8(0, 0);
    STAGE8(1, 1);

    for (int kt = 0; kt < NT; kt++) {
        const int bb = kt & 1;
        if (kt < NT - 1)
            asm volatile("s_waitcnt vmcnt(8)" ::: "memory");
        else
            asm volatile("s_waitcnt vmcnt(0)" ::: "memory");
        __builtin_amdgcn_s_barrier();           // all waves confirmed tile kt
        asm volatile("" ::: "memory");

        #pragma unroll
        for (int tt = 0; tt < 2; tt++) {
            bf16x8 af[8], bf[4];
            #pragma unroll
            for (int i = 0; i < 8; i++) {
                int row = wm + i * 16 + l16;
                af[i] = *(const bf16x8*)&As[bb][row * 64 + ((((tt << 2) + quad) ^ (row & 7)) << 3)];
            }
            #pragma unroll
            for (int j = 0; j < 4; j++) {
                int row = wn + j * 16 + l16;
                bf[j] = *(const bf16x8*)&Bs[bb][row * 64 + ((((tt << 2) + quad) ^ (row & 7)) << 3)];
            }
            #pragma unroll
            for (int i = 0; i < 8; i++)
                #pragma unroll
                for (int j = 0; j < 4; j++)
                    acc[i][j] = __builtin_amdgcn_mfma_f32_16x16x32_bf16(
                        af[i], bf[j], acc[i][j], 0, 0, 0);
        }

        asm volatile("" ::: "memory");
        __builtin_amdgcn_s_barrier();
        asm volatile("" ::: "memory");
        if (kt + 2 < NT)
            STAGE8(kt + 2, bb);
    }

    // ---- epilogue ----
    if (VT && n0 >= 1024) {
        #pragma unroll
        for (int i = 0; i < 8; i++) {
            int mbase = m0 + wm + i * 16 + quad * 4;
            int b = mbase >> 9, s = mbase & 511;
            #pragma unroll
            for (int j = 0; j < 4; j++) {
                int n = n0 + wn + j * 16 + l16;
                int hv = n - 1024;
                int h = hv >> 6, vd = hv & 63;
                float bv = bias[n];
                ushort4 pk;
                pk.x = f2bs(acc[i][j][0] + bv);
                pk.y = f2bs(acc[i][j][1] + bv);
                pk.z = f2bs(acc[i][j][2] + bv);
                pk.w = f2bs(acc[i][j][3] + bv);
                *(ushort4*)&vt[((size_t)((b << 3) + h)) * 32768 + (size_t)vd * 512 + s] = pk;
            }
        }
        return;
    }

    #pragma unroll
    for (int i = 0; i < 8; i++)
        #pragma unroll
        for (int j = 0; j < 4; j++) {
            int n = n0 + wn + j * 16 + l16;
            float bv = bias[n];
            #pragma unroll
            for (int r = 0; r < 4; r++) {
                int m = m0 + wm + i * 16 + quad * 4 + r;
                float v = acc[i][j][r] + bv;
                if (RELU) v = fmaxf(v, 0.f);
                C[(size_t)m * ldc + n] = f2bs(v);
            }
        }
}

// ---------------------------------------------------------------------------
// Full-row GEMM + bias + residual + LayerNorm fused. BM=32, BN=512 (block
// owns complete rows -> LN entirely in-block). Grid = M/32 = 256 blocks =
// 1/CU. 4 waves; wave-tile 32x128 (MI=2, NJ=8). Same counted-vmcnt pipeline
// as gemm8; per-wave staging = 1 (A) + 16 (B) = 17 insts -> vmcnt(17).
// A:[m][k] lda; B:[n][k] ldb=K; res/X: [m][512] bf16 (in-place safe: each
// (row,n) read+written by exactly one thread, read-before-write).
__global__ __launch_bounds__(256) void gemmLN(
    const ushort_t* __restrict__ A, const ushort_t* __restrict__ B,
    const float* __restrict__ bias, const ushort_t* __restrict__ res,
    const float* __restrict__ g, const float* __restrict__ bt,
    ushort_t* __restrict__ X, int K, int lda)
{
    __shared__ ushort_t As[2][32 * 64];
    __shared__ ushort_t Bs[2][512 * 64];
    __shared__ float2 pst[4][32];
    __shared__ float2 rmv[32];

    const int t = threadIdx.x;
    const int lane = t & 63, w = t >> 6;        // 4 waves
    const int l16 = lane & 15, quad = lane >> 4;
    const int r8 = lane >> 3;
    const int kg = ((lane & 7) ^ r8) << 3;
    const int wn = w * 128;
    const int m0 = blockIdx.x * 32;
    const int NT = K >> 6;

    f32x4 acc[2][8];
    #pragma unroll
    for (int i = 0; i < 2; i++)
        #pragma unroll
        for (int j = 0; j < 8; j++)
            acc[i][j] = (f32x4){0.f, 0.f, 0.f, 0.f};

    auto STAGE = [&](int kt, int bb) {
        int k0 = kt << 6;
        g2lds16(A + (size_t)(m0 + w * 8 + r8) * lda + k0 + kg,
                &As[bb][(w * 8) * 64]);
        #pragma unroll
        for (int ii = 0; ii < 16; ii++) {
            int rbase = w * 128 + ii * 8;
            g2lds16(B + (size_t)(rbase + r8) * K + k0 + kg,
                    &Bs[bb][rbase * 64]);
        }
    };

    STAGE(0, 0);
    STAGE(1, 1);

    for (int kt = 0; kt < NT; kt++) {
        const int bb = kt & 1;
        if (kt < NT - 1)
            asm volatile("s_waitcnt vmcnt(17)" ::: "memory");
        else
            asm volatile("s_waitcnt vmcnt(0)" ::: "memory");
        __builtin_amdgcn_s_barrier();
        asm volatile("" ::: "memory");

        #pragma unroll
        for (int tt = 0; tt < 2; tt++) {
            bf16x8 af[2], bf8[8];
            #pragma unroll
            for (int i = 0; i < 2; i++) {
                int row = i * 16 + l16;
                af[i] = *(const bf16x8*)&As[bb][row * 64 + ((((tt << 2) + quad) ^ (row & 7)) << 3)];
            }
            #pragma unroll
            for (int j = 0; j < 8; j++) {
                int row = wn + j * 16 + l16;
                bf8[j] = *(const bf16x8*)&Bs[bb][row * 64 + ((((tt << 2) + quad) ^ (row & 7)) << 3)];
            }
            #pragma unroll
            for (int i = 0; i < 2; i++)
                #pragma unroll
                for (int j = 0; j < 8; j++)
                    acc[i][j] = __builtin_amdgcn_mfma_f32_16x16x32_bf16(
                        af[i], bf8[j], acc[i][j], 0, 0, 0);
        }

        asm volatile("" ::: "memory");
        __builtin_amdgcn_s_barrier();
        asm volatile("" ::: "memory");
        if (kt + 2 < NT)
            STAGE(kt + 2, bb);
    }

    // ---- epilogue: v = acc + bias + residual; LN over full 512-row ----
    float rs[2][4], rq[2][4];
    #pragma unroll
    for (int i = 0; i < 2; i++)
        #pragma unroll
        for (int r = 0; r < 4; r++) { rs[i][r] = 0.f; rq[i][r] = 0.f; }

    #pragma unroll
    for (int i = 0; i < 2; i++)
        #pragma unroll
        for (int j = 0; j < 8; j++) {
            int n = wn + j * 16 + l16;
            float bvn = bias[n];
            #pragma unroll
            for (int r = 0; r < 4; r++) {
                int row = i * 16 + quad * 4 + r;
                float v = acc[i][j][r] + bvn
                        + bs2f(res[(size_t)(m0 + row) * 512 + n]);
                acc[i][j][r] = v;
                rs[i][r] += v;
                rq[i][r] += v * v;
            }
        }

    #pragma unroll
    for (int i = 0; i < 2; i++)
        #pragma unroll
        for (int r = 0; r < 4; r++) {
            #pragma unroll
            for (int off = 1; off < 16; off <<= 1) {
                rs[i][r] += __shfl_xor(rs[i][r], off);
                rq[i][r] += __shfl_xor(rq[i][r], off);
            }
            if (l16 == 0)
                pst[w][i * 16 + quad * 4 + r] = make_float2(rs[i][r], rq[i][r]);
        }
    __syncthreads();
    if (t < 32) {
        float s = 0.f, q = 0.f;
        #pragma unroll
        for (int wv = 0; wv < 4; wv++) {
            float2 p = pst[wv][t];
            s += p.x; q += p.y;
        }
        float mean = s * (1.f / 512.f);
        float var = q * (1.f / 512.f) - mean * mean;
        rmv[t] = make_float2(mean, rsqrtf(var + 1e-5f));
    }
    __syncthreads();

    #pragma unroll
    for (int i = 0; i < 2; i++)
        #pragma unroll
        for (int j = 0; j < 8; j++) {
            int n = wn + j * 16 + l16;
            float gn = g[n], btn = bt[n];
            #pragma unroll
            for (int r = 0; r < 4; r++) {
                int row = i * 16 + quad * 4 + r;
                float2 mr = rmv[row];
                float o = (acc[i][j][r] - mr.x) * mr.y * gn + btn;
                X[(size_t)(m0 + row) * 512 + n] = f2bs(o);
            }
        }
}

// ---------------------------------------------------------------------------
// Fused flash attention (unchanged): one (b,h), 128 q rows/block,
// 4 key-chunks of 128, fixed softmax reference m=0, ctx in-place into Q slice.
__global__ __launch_bounds__(256) void flash_attn(
    ushort_t* __restrict__ QKV, const ushort_t* __restrict__ Vt,
    const int* __restrict__ tok)
{
    __shared__ ushort_t Qs[128 * 64];
    __shared__ ushort_t Ks[128 * 64];
    __shared__ ushort_t Vts[64 * 128];
    __shared__ ushort_t Ps[128 * 128];

    const int bh = blockIdx.y;
    const int b = bh >> 3, h = bh & 7;
    const int q0 = blockIdx.x * 128;
    const int t = threadIdx.x;
    const int lane = t & 63, w = t >> 6;
    const int l16 = lane & 15, quad = lane >> 4;
    const int wm = w * 32;
    const size_t rowbase = (size_t)b * 512;

    {
        int r8 = lane >> 3;
        int kg = (lane & 7) ^ r8;
        #pragma unroll
        for (int ii = 0; ii < 4; ii++) {
            int rb = w * 32 + ii * 8;
            g2lds16(QKV + (rowbase + q0 + rb + r8) * 1536 + h * 64 + kg * 8,
                    &Qs[rb * 64]);
        }
    }

    f32x4 accO[2][4];
    #pragma unroll
    for (int i = 0; i < 2; i++)
        #pragma unroll
        for (int jv = 0; jv < 4; jv++)
            accO[i][jv] = (f32x4){0.f, 0.f, 0.f, 0.f};
    float lrow[2][4];
    #pragma unroll
    for (int i = 0; i < 2; i++)
        #pragma unroll
        for (int r = 0; r < 4; r++) lrow[i][r] = 0.f;

    for (int kc = 0; kc < 4; kc++) {
        __syncthreads();
        {
            int r8 = lane >> 3;
            int kg = (lane & 7) ^ r8;
            #pragma unroll
            for (int ii = 0; ii < 4; ii++) {
                int rb = w * 32 + ii * 8;
                g2lds16(QKV + (rowbase + kc * 128 + rb + r8) * 1536 + 512 + h * 64 + kg * 8,
                        &Ks[rb * 64]);
            }
        }
        {
            int v4 = lane >> 4;
            #pragma unroll
            for (int ii = 0; ii < 4; ii++) {
                int vb = w * 16 + ii * 4;
                int vd = vb + v4;
                int kg = (lane & 15) ^ (vd & 15);
                g2lds16(Vt + (size_t)bh * 32768 + (size_t)vd * 512 + kc * 128 + kg * 8,
                        &Vts[vb * 128]);
            }
        }
        float maskv[8];
        #pragma unroll
        for (int j = 0; j < 8; j++)
            maskv[j] = (tok[b * 512 + kc * 128 + j * 16 + l16] == 0) ? -1e9f : 0.f;

        __syncthreads();

        f32x4 sacc[2][8];
        #pragma unroll
        for (int i = 0; i < 2; i++)
            #pragma unroll
            for (int j = 0; j < 8; j++)
                sacc[i][j] = (f32x4){0.f, 0.f, 0.f, 0.f};
        #pragma unroll
        for (int tt = 0; tt < 2; tt++) {
            bf16x8 aq[2], bk8[8];
            #pragma unroll
            for (int i = 0; i < 2; i++) {
                int row = wm + i * 16 + l16;
                aq[i] = *(const bf16x8*)&Qs[row * 64 + (((tt << 2) + quad) ^ (row & 7)) * 8];
            }
            #pragma unroll
            for (int j = 0; j < 8; j++) {
                int row = j * 16 + l16;
                bk8[j] = *(const bf16x8*)&Ks[row * 64 + (((tt << 2) + quad) ^ (row & 7)) * 8];
            }
            #pragma unroll
            for (int i = 0; i < 2; i++)
                #pragma unroll
                for (int j = 0; j < 8; j++)
                    sacc[i][j] = __builtin_amdgcn_mfma_f32_16x16x32_bf16(
                        aq[i], bk8[j], sacc[i][j], 0, 0, 0);
        }

        #pragma unroll
        for (int i = 0; i < 2; i++)
            #pragma unroll
            for (int j = 0; j < 8; j++)
                #pragma unroll
                for (int r = 0; r < 4; r++) {
                    float p = __expf(fmaf(sacc[i][j][r], SCALE_QK, maskv[j]));
                    sacc[i][j][r] = p;
                    lrow[i][r] += p;
                }

        #pragma unroll
        for (int i = 0; i < 2; i++)
            #pragma unroll
            for (int j = 0; j < 8; j++) {
                int col = j * 16 + l16;
                int colc = col >> 3, csub = col & 7;
                #pragma unroll
                for (int r = 0; r < 4; r++) {
                    int row = wm + i * 16 + quad * 4 + r;
                    Ps[row * 128 + ((colc ^ (row & 15)) << 3) + csub] = f2bs(sacc[i][j][r]);
                }
            }

        #pragma unroll
        for (int tt = 0; tt < 4; tt++) {
            bf16x8 ap[2], bv8[4];
            #pragma unroll
            for (int i = 0; i < 2; i++) {
                int row = wm + i * 16 + l16;
                ap[i] = *(const bf16x8*)&Ps[row * 128 + ((((tt << 2) + quad)) ^ (row & 15)) * 8];
            }
            #pragma unroll
            for (int jv = 0; jv < 4; jv++) {
                int vd = jv * 16 + l16;
                bv8[jv] = *(const bf16x8*)&Vts[vd * 128 + (((tt << 2) + quad) ^ (vd & 15)) * 8];
            }
            #pragma unroll
            for (int i = 0; i < 2; i++)
                #pragma unroll
                for (int jv = 0; jv < 4; jv++)
                    accO[i][jv] = __builtin_amdgcn_mfma_f32_16x16x32_bf16(
                        ap[i], bv8[jv], accO[i][jv], 0, 0, 0);
        }
    }

    #pragma unroll
    for (int i = 0; i < 2; i++)
        #pragma unroll
        for (int r = 0; r < 4; r++) {
            float s = lrow[i][r];
            #pragma unroll
            for (int off = 1; off < 16; off <<= 1)
                s += __shfl_xor(s, off);
            float inv = 1.f / s;
            int row = q0 + wm + i * 16 + quad * 4 + r;
            #pragma unroll
            for (int jv = 0; jv < 4; jv++) {
                int vd = jv * 16 + l16;
                QKV[(rowbase + row) * 1536 + h * 64 + vd] = f2bs(accO[i][jv][r] * inv);
            }
        }
}

// ---------------------------------------------------------------------------
// prep: all weight transposes (f32 -> bf16, [R][C] -> [C][R]) + concat_bias
// + Fb zero + embed+PE in ONE dispatch (blockIdx ranges).
__global__ __launch_bounds__(256) void prep(
    const float* __restrict__ Wq, const float* __restrict__ Wk,
    const float* __restrict__ Wv, const float* __restrict__ Wo,
    const float* __restrict__ W1, const float* __restrict__ W2,
    const float* __restrict__ bq, const float* __restrict__ bk,
    const float* __restrict__ bv, const int* __restrict__ tok,
    const float* __restrict__ emb,
    __hip_bfloat16* __restrict__ WqkvT, __hip_bfloat16* __restrict__ WoT,
    __hip_bfloat16* __restrict__ W1T, __hip_bfloat16* __restrict__ W2T,
    float* __restrict__ bqkv, float* __restrict__ Fb,
    __hip_bfloat16* __restrict__ xb)
{
    const int blk = blockIdx.x;
    const int t = threadIdx.x;

    if (blk < 12288) {                          // ---- weight transposes ----
        __shared__ float tile[32][33];
        const float* in; __hip_bfloat16* out;
        long long inz, outz; int R, Cc, bx, by, bz;
        if (blk < 4096) {                       // Wq/Wk/Wv/Wo: 512x512, 16x16x4
            int seg = blk >> 10, lb = blk & 1023;
            bz = lb >> 8; by = (lb >> 4) & 15; bx = lb & 15;
            R = 512; Cc = 512; inz = 262144;
            if      (seg == 0) { in = Wq; out = WqkvT;          outz = 786432; }
            else if (seg == 1) { in = Wk; out = WqkvT + 262144; outz = 786432; }
            else if (seg == 2) { in = Wv; out = WqkvT + 524288; outz = 786432; }
            else               { in = Wo; out = WoT;            outz = 262144; }
        } else if (blk < 8192) {                // W1: 512x2048, 64x16x4
            int lb = blk - 4096;
            bz = lb >> 10; by = (lb >> 6) & 15; bx = lb & 63;
            R = 512; Cc = 2048; inz = 1048576; outz = 1048576;
            in = W1; out = W1T;
        } else {                                // W2: 2048x512, 16x64x4
            int lb = blk - 8192;
            bz = lb >> 10; by = (lb >> 4) & 63; bx = lb & 15;
            R = 2048; Cc = 512; inz = 1048576; outz = 1048576;
            in = W2; out = W2T;
        }
        in += bz * inz; out += bz * outz;
        int c0 = bx * 32, r0 = by * 32;
        int tx = t & 31, ty = t >> 5;
        #pragma unroll
        for (int i = 0; i < 4; i++)
            tile[ty + i * 8][tx] = in[(size_t)(r0 + ty + i * 8) * Cc + c0 + tx];
        __syncthreads();
        #pragma unroll
        for (int i = 0; i < 4; i++)
            out[(size_t)(c0 + ty + i * 8) * R + r0 + tx] =
                __float2bfloat16(tile[tx][ty + i * 8]);
    } else if (blk < 12312) {                   // ---- concat_bias + Fb=0 ----
        int k = blk - 12288;
        int idx = k * 256 + t;                  // < 6144 = 4*1536
        int l = idx / 1536, n = idx - l * 1536;
        float v = (n < 512) ? bq[l * 512 + n]
                : (n < 1024) ? bk[l * 512 + n - 512]
                             : bv[l * 512 + n - 1024];
        bqkv[idx] = v;
        if (k < 8) Fb[k * 256 + t] = 0.f;
    } else {                                    // ---- embed + PE ----
        int idx = (blk - 12312) * 256 + t;
        int d  = idx & 511;
        int bs = idx >> 9;
        int s  = bs & 511;
        int tk = tok[bs];
        float freq  = expf(-(float)(d & ~1) * PE_C);
        float angle = (float)s * freq;
        float pe    = (d & 1) ? cosf(angle) : sinf(angle);
        xb[idx] = __float2bfloat16(emb[(size_t)tk * 512 + d] + pe);
    }
}

// ---------------------------------------------------------------------------
// head stage 1: 512 k-slices of 512; per-block LDS reduce across the 8
// k-half groups, then 2048 global atomicAdds into Fb (zeroed by prep).
__global__ __launch_bounds__(256) void feat_partial(const ushort_t* __restrict__ Xb,
                                                    const float* __restrict__ Wf,
                                                    float* __restrict__ Fb) {
    int slice = blockIdx.x;
    int k0 = slice * 512;
    __shared__ float Xs[16][512];
    __shared__ float Red[2048];
    int t = threadIdx.x;
    for (int i = t; i < 2048; i += 256) {
        int b = i >> 7, c4 = (i & 127) * 4;
        ushort4 u = *(const ushort4*)&Xb[(size_t)b * 262144 + k0 + c4];
        Xs[b][c4 + 0] = bs2f(u.x);
        Xs[b][c4 + 1] = bs2f(u.y);
        Xs[b][c4 + 2] = bs2f(u.z);
        Xs[b][c4 + 3] = bs2f(u.w);
        Red[i] = 0.f;
    }
    __syncthreads();
    int n4 = (t & 31) * 4;
    int kh = t >> 5;
    float4 acc[16];
    #pragma unroll
    for (int b = 0; b < 16; b++) acc[b] = (float4){0.f, 0.f, 0.f, 0.f};
    for (int kk4 = 0; kk4 < 16; kk4++) {
        int kb = kh * 64 + kk4 * 4;
        float4 w0 = *(const float4*)&Wf[(size_t)(k0 + kb + 0) * 128 + n4];
        float4 w1 = *(const float4*)&Wf[(size_t)(k0 + kb + 1) * 128 + n4];
        float4 w2 = *(const float4*)&Wf[(size_t)(k0 + kb + 2) * 128 + n4];
        float4 w3 = *(const float4*)&Wf[(size_t)(k0 + kb + 3) * 128 + n4];
        #pragma unroll
        for (int b = 0; b < 16; b++) {
            float4 xq = *(const float4*)&Xs[b][kb];
            acc[b].x += xq.x * w0.x + xq.y * w1.x + xq.z * w2.x + xq.w * w3.x;
            acc[b].y += xq.x * w0.y + xq.y * w1.y + xq.z * w2.y + xq.w * w3.y;
            acc[b].z += xq.x * w0.z + xq.y * w1.z + xq.z * w2.z + xq.w * w3.z;
            acc[b].w += xq.x * w0.w + xq.y * w1.w + xq.z * w2.w + xq.w * w3.w;
        }
    }
    #pragma unroll
    for (int b = 0; b < 16; b++) {
        atomicAdd(&Red[b * 128 + n4 + 0], acc[b].x);
        atomicAdd(&Red[b * 128 + n4 + 1], acc[b].y);
        atomicAdd(&Red[b * 128 + n4 + 2], acc[b].z);
        atomicAdd(&Red[b * 128 + n4 + 3], acc[b].w);
    }
    __syncthreads();
    for (int o = t; o < 2048; o += 256)
        atomicAdd(&Fb[o], Red[o]);
}

// out: [0..15]=y_score, [16..31]=y_pred, [32..2079]=features
__global__ __launch_bounds__(256) void head_kernel(const float* __restrict__ feat,
                                                   const float* __restrict__ bfv,
                                                   const float* __restrict__ Wo2,
                                                   const float* __restrict__ bo2,
                                                   float* __restrict__ out) {
    __shared__ float f[2048];
    int t = threadIdx.x;
    for (int i = t; i < 2048; i += 256) {
        float v = feat[i] + bfv[i & 127];
        f[i] = v;
        out[32 + i] = v;
    }
    __syncthreads();
    if (t < 16) {
        float zv = bo2[0];
        for (int n = 0; n < 128; n++) zv = fmaf(f[t * 128 + n], Wo2[n], zv);
        float ys = 1.f / (1.f + expf(-zv));
        out[t] = ys;
        out[16 + t] = rintf(ys);
    }
}

// ---------------------------------------------------------------------------
extern "C" void kernel_launch(void* const* d_in, const int* in_sizes, int n_in,
                              void* d_out, int out_size, void* d_ws, size_t ws_size,
                              hipStream_t stream) {
    const int*   enc  = (const int*)  d_in[0];
    const float* emb  = (const float*)d_in[1];
    const float* Wq   = (const float*)d_in[2];
    const float* bq   = (const float*)d_in[3];
    const float* Wk   = (const float*)d_in[4];
    const float* bk   = (const float*)d_in[5];
    const float* Wv   = (const float*)d_in[6];
    const float* bv   = (const float*)d_in[7];
    const float* Wo   = (const float*)d_in[8];
    const float* bo   = (const float*)d_in[9];
    const float* g1   = (const float*)d_in[10];
    const float* be1  = (const float*)d_in[11];
    const float* W1   = (const float*)d_in[12];
    const float* b1f  = (const float*)d_in[13];
    const float* W2   = (const float*)d_in[14];
    const float* b2f  = (const float*)d_in[15];
    const float* g2   = (const float*)d_in[16];
    const float* be2  = (const float*)d_in[17];
    const float* Wf   = (const float*)d_in[18];
    const float* bf   = (const float*)d_in[19];
    const float* Wout = (const float*)d_in[20];
    const float* bout = (const float*)d_in[21];
    float* out = (float*)d_out;

    // ---- workspace layout (bytes), peak < 119 MB ----
    char* ws = (char*)d_ws;
    ushort_t* Xb   = (ushort_t*) (ws + 16777216);    // [8192,512] bf16 activations
    ushort_t* QKV  = (ushort_t*) (ws + 25165824);    // [8192,1536] bf16
    ushort_t* Vt   = (ushort_t*) (ws + 50331648);    // [128][64][512] bf16
    ushort_t* S    = (ushort_t*) (ws + 58720256);    // FFN hidden [8192][2048] bf16
    ushort_t* WqkvT= (ushort_t*) (ws + 92274688);    // [4][1536][512] bf16
    ushort_t* WoT  = (ushort_t*) (ws + 98566144);    // [4][512][512] bf16
    ushort_t* W1T  = (ushort_t*) (ws + 100663296);   // [4][2048][512] bf16
    ushort_t* W2T  = (ushort_t*) (ws + 109051904);   // [4][512][2048] bf16
    float*    bqkv = (float*)    (ws + 117440512);   // [4][1536]
    float*    Fb   = (float*)    (ws + 117465088);   // [16][128]

    typedef __hip_bfloat16 bf16;

    // one dispatch: 12288 transpose blocks + 24 concat blocks + 16384 embed
    prep<<<28696, 256, 0, stream>>>(
        Wq, Wk, Wv, Wo, W1, W2, bq, bk, bv, enc, emb,
        (bf16*)WqkvT, (bf16*)WoT, (bf16*)W1T, (bf16*)W2T, bqkv, Fb, (bf16*)Xb);

    for (int l = 0; l < 4; l++) {
        // QKV: [8192,512]x[512,1536]; V columns go transposed straight to Vt
        gemm8<false, true><<<dim3(6, 32), 512, 0, stream>>>(
            Xb, WqkvT + (size_t)l * 786432, bqkv + l * 1536,
            QKV, Vt, 512, 512, 512, 1536);

        flash_attn<<<dim3(4, 128), 256, 0, stream>>>(QKV, Vt, enc);

        // Wo + bo + residual + LN1 fused -> Xb
        gemmLN<<<256, 256, 0, stream>>>(
            QKV, WoT + (size_t)l * 262144, bo + l * 512, Xb,
            g1 + l * 512, be1 + l * 512, Xb, 512, 1536);

        // FFN1: relu(Xb @ W1T + b1) -> S bf16
        gemm8<true, false><<<dim3(8, 32), 512, 0, stream>>>(
            Xb, W1T + (size_t)l * 1048576, b1f + l * 2048,
            S, nullptr, 512, 512, 512, 2048);

        // FFN2 + b2 + residual + LN2 fused -> Xb
        gemmLN<<<256, 256, 0, stream>>>(
            S, W2T + (size_t)l * 1048576, b2f + l * 512, Xb,
            g2 + l * 512, be2 + l * 512, Xb, 2048, 2048);
    }

    feat_partial<<<512, 256, 0, stream>>>(Xb, Wf, Fb);
    head_kernel<<<1, 256, 0, stream>>>(Fb, bf, Wout, bout, out);
}